// Round 14
// baseline (57.824 us; speedup 1.0000x reference)
//
#include <hip/hip_runtime.h>
#include <hip/hip_bf16.h>

#define NMOV 32768
#define LW 15
#define DIM 256
#define NVOC 27
#define NR 405       // NVOC * LW distinct (letter, position) rows
#define GSH 408      // row stride of H in float2 units
#define MPB 16       // moves per block in moves_kernel
#define NEP 550      // EP2 rows: 450 vec combos + 100 score rows

__device__ __forceinline__ float b2f(unsigned short u) {
    return __uint_as_float(((unsigned int)u) << 16);
}
__device__ __forceinline__ unsigned short f2bu(float x) {
    __hip_bfloat16 h = __float2bfloat16(x);
    return *reinterpret_cast<unsigned short*>(&h);
}

// pair index p -> (l<<4 | m), l >= m, p = l(l+1)/2 + m
__device__ const unsigned char PAIR_LUT[120] = {
    0x00,
    0x10,0x11,
    0x20,0x21,0x22,
    0x30,0x31,0x32,0x33,
    0x40,0x41,0x42,0x43,0x44,
    0x50,0x51,0x52,0x53,0x54,0x55,
    0x60,0x61,0x62,0x63,0x64,0x65,0x66,
    0x70,0x71,0x72,0x73,0x74,0x75,0x76,0x77,
    0x80,0x81,0x82,0x83,0x84,0x85,0x86,0x87,0x88,
    0x90,0x91,0x92,0x93,0x94,0x95,0x96,0x97,0x98,0x99,
    0xA0,0xA1,0xA2,0xA3,0xA4,0xA5,0xA6,0xA7,0xA8,0xA9,0xAA,
    0xB0,0xB1,0xB2,0xB3,0xB4,0xB5,0xB6,0xB7,0xB8,0xB9,0xBA,0xBB,
    0xC0,0xC1,0xC2,0xC3,0xC4,0xC5,0xC6,0xC7,0xC8,0xC9,0xCA,0xCB,0xCC,
    0xD0,0xD1,0xD2,0xD3,0xD4,0xD5,0xD6,0xD7,0xD8,0xD9,0xDA,0xDB,0xDC,0xDD,
    0xE0,0xE1,0xE2,0xE3,0xE4,0xE5,0xE6,0xE7,0xE8,0xE9,0xEA,0xEB,0xEC,0xED,0xEE
};

// ---------------------------------------------------------------------------
// Kernel 1 v6: QKV GEMM, 32x32 tiles + 2x2 micro-tile (0.5 FLOP/LDS-byte,
// half the LDS traffic of the 16x16 version), plain stores, full K streamed
// in BK=64 chunks. Blocks [0,312): gemm (13 row-tiles x 24 col-tiles).
// Blocks [312,450): build EP2[550][256] bf16 — rows 0-449:
// row_emb[r]+col_emb[c]+dir_emb[d] (v=r*30+c*2+d); rows 450-549: score_emb.
// ---------------------------------------------------------------------------
__global__ __launch_bounds__(256) void qkv_gemm(
    const float* __restrict__ le, const float* __restrict__ pos,
    const float* __restrict__ Wq, const float* __restrict__ bq,
    const float* __restrict__ Wk, const float* __restrict__ bk,
    const float* __restrict__ Wv, const float* __restrict__ bv,
    const float* __restrict__ row_emb, const float* __restrict__ col_emb,
    const float* __restrict__ dir_emb, const float* __restrict__ score_emb,
    float* __restrict__ QT, float* __restrict__ KT,
    __hip_bfloat16* __restrict__ VT, __hip_bfloat16* __restrict__ EP2)
{
    const int t = threadIdx.x;
    if (blockIdx.x >= 312) {
        int idx = (blockIdx.x - 312) * 1024 + t * 4;   // 4 elems, same row
        if (idx < NEP * DIM) {
            int v = idx >> 8, dcol = idx & 255;
            float4 s4;
            if (v < 450) {
                int r = v / 30, rm = v % 30, c = rm >> 1, d = rm & 1;
                float4 a = *(const float4*)&row_emb[r * DIM + dcol];
                float4 b = *(const float4*)&col_emb[c * DIM + dcol];
                float4 e = *(const float4*)&dir_emb[d * DIM + dcol];
                s4 = make_float4(a.x + b.x + e.x, a.y + b.y + e.y,
                                 a.z + b.z + e.z, a.w + b.w + e.w);
            } else {
                s4 = *(const float4*)&score_emb[(v - 450) * DIM + dcol];
            }
            ushort4 o;
            o.x = f2bu(s4.x); o.y = f2bu(s4.y);
            o.z = f2bu(s4.z); o.w = f2bu(s4.w);
            *(ushort4*)((unsigned short*)EP2 + idx) = o;
        }
        return;
    }

    __shared__ float Ash[32][68];
    __shared__ float Bsh[32][68];
    const int bx = blockIdx.x % 24;
    const int by = blockIdx.x / 24;
    const int r0 = by * 32;
    const int mat = bx >> 3;             // 0=Q 1=K 2=V
    const int nb  = (bx & 7) * 32;       // col base within mat
    const float* W  = (mat == 0) ? Wq : (mat == 1) ? Wk : Wv;
    const float* bb = (mat == 0) ? bq : (mat == 1) ? bk : bv;

    const int ti = t >> 4, tj = t & 15;
    float acc00 = 0.f, acc01 = 0.f, acc10 = 0.f, acc11 = 0.f;

    for (int k0 = 0; k0 < DIM; k0 += 64) {
        #pragma unroll
        for (int s = 0; s < 2; ++s) {
            int slot = s * 256 + t;      // 512 float4 slots per tile
            int row = slot >> 4, c4 = slot & 15;
            int r = r0 + row;
            float4 va = make_float4(0.f, 0.f, 0.f, 0.f);
            if (r < NR) {
                int c = r / 15, l = r - c * 15;
                float4 lv = *(const float4*)&le[c * DIM + k0 + c4 * 4];
                float4 pv = *(const float4*)&pos[l * DIM + k0 + c4 * 4];
                va = make_float4(lv.x + pv.x, lv.y + pv.y, lv.z + pv.z, lv.w + pv.w);
            }
            *(float4*)&Ash[row][c4 * 4] = va;
            float4 vb = *(const float4*)&W[(nb + row) * DIM + k0 + c4 * 4];
            *(float4*)&Bsh[row][c4 * 4] = vb;
        }
        __syncthreads();
        #pragma unroll 4
        for (int kk = 0; kk < 64; kk += 4) {
            float4 a0 = *(const float4*)&Ash[2 * ti][kk];
            float4 a1 = *(const float4*)&Ash[2 * ti + 1][kk];
            float4 b0 = *(const float4*)&Bsh[tj][kk];
            float4 b1 = *(const float4*)&Bsh[tj + 16][kk];
            acc00 += a0.x * b0.x + a0.y * b0.y + a0.z * b0.z + a0.w * b0.w;
            acc01 += a0.x * b1.x + a0.y * b1.y + a0.z * b1.z + a0.w * b1.w;
            acc10 += a1.x * b0.x + a1.y * b0.y + a1.z * b0.z + a1.w * b0.w;
            acc11 += a1.x * b1.x + a1.y * b1.y + a1.z * b1.z + a1.w * b1.w;
        }
        __syncthreads();
    }

    const int c0 = nb + tj, c1 = nb + tj + 16;
    const float bias0 = bb[c0], bias1 = bb[c1];
    #pragma unroll
    for (int rr = 0; rr < 2; ++rr) {
        int r = r0 + 2 * ti + rr;
        if (r < NR) {
            float v0 = (rr == 0 ? acc00 : acc10) + bias0;
            float v1 = (rr == 0 ? acc01 : acc11) + bias1;
            if (mat == 0) {
                QT[r * DIM + c0] = v0; QT[r * DIM + c1] = v1;
            } else if (mat == 1) {
                KT[r * DIM + c0] = v0; KT[r * DIM + c1] = v1;
            } else {
                VT[r * DIM + c0] = __float2bfloat16(v0);
                VT[r * DIM + c1] = __float2bfloat16(v1);
            }
        }
    }
}

// ---------------------------------------------------------------------------
// Kernel 2 v4 (unchanged from R13): UNPAIRED H tiles, 676 blocks.
// Block (bi,bj) computes g(i,j) and writes H[i][j].x and H[j][i].y
// (disjoint fields; diagonal blocks write each field once — idempotent-safe).
// ---------------------------------------------------------------------------
__global__ __launch_bounds__(256) void h_matrix(
    const float* __restrict__ QT, const float* __restrict__ KT,
    float2* __restrict__ H)
{
    __shared__ float Qs[16][68], Ks[16][68], Ts[16][17];
    const int bi = blockIdx.x / 26, bj = blockIdx.x % 26;
    const int i0 = bi * 16, j0 = bj * 16;
    const int t = threadIdx.x;
    const int ti = t >> 4, tj = t & 15;

    float acc = 0.f;
    for (int k0 = 0; k0 < DIM; k0 += 64) {
        #pragma unroll
        for (int s = 0; s < 2; ++s) {
            int lin = s * 256 + t;           // 512 float4 slots
            int tile = lin >> 8;             // 0=Q 1=K
            int r    = (lin >> 4) & 15;
            int c4   = lin & 15;
            int grow = tile ? (j0 + r) : (i0 + r);
            const float* src = tile ? KT : QT;
            float4 v = (grow < NR)
                ? *(const float4*)&src[grow * DIM + k0 + c4 * 4]
                : make_float4(0.f, 0.f, 0.f, 0.f);
            float* dst = tile ? &Ks[r][c4 * 4] : &Qs[r][c4 * 4];
            *(float4*)dst = v;
        }
        __syncthreads();
        #pragma unroll 4
        for (int k = 0; k < 64; k += 4) {
            float4 q = *(const float4*)&Qs[ti][k];
            float4 kk = *(const float4*)&Ks[tj][k];
            acc += q.x * kk.x + q.y * kk.y + q.z * kk.z + q.w * kk.w;
        }
        __syncthreads();
    }

    const int i1 = i0 + ti, j1 = j0 + tj;
    if (i1 < NR && j1 < NR) ((float*)&H[i1 * GSH + j1])[0] = acc;

    Ts[ti][tj] = acc;
    __syncthreads();
    const float tr = Ts[tj][ti];             // = g(i0+tj, j0+ti)
    const int j2 = j0 + ti, i2 = i0 + tj;
    if (j2 < NR && i2 < NR) ((float*)&H[j2 * GSH + i2])[1] = tr;
}

// ---------------------------------------------------------------------------
// Kernel 3 (unchanged from R13): wave-synchronous, ZERO __syncthreads,
// bf16 VT/EP2, phase-2 unroll 2. VGPR must stay under the 64 cliff (R11).
// NOTE: __launch_bounds__(256) ONLY — a min-waves arg spills to scratch (R4).
// ---------------------------------------------------------------------------
__global__ __launch_bounds__(256) void moves_kernel(
    const int* __restrict__ words, const int* __restrict__ rowsI,
    const int* __restrict__ colsI, const int* __restrict__ dirsI,
    const int* __restrict__ scoresI,
    const float2* __restrict__ H, const __hip_bfloat16* __restrict__ VT,
    const __hip_bfloat16* __restrict__ EP2,
    float* __restrict__ out)
{
    __shared__ float S[MPB][LW][17];     // 15x15 score matrix per move (padded)
    __shared__ int   rIdx[MPB][16];      // row indices per move
    __shared__ float csum[MPB][16];      // per-move column sums
    __shared__ int   meta[MPB][2];       // EP2 row indices: vec, score
    const int base = blockIdx.x * MPB;
    const int t  = threadIdx.x;
    const int w  = t >> 6;               // wave id: owns moves 4w..4w+3
    const int ln = t & 63;
    const int hw = t >> 5;               // half-wave: owns moves 2hw, 2hw+1
    const int j  = t & 31;

    // rIdx + meta loaded by the OWNING wave's lanes (wave-local LDS)
    if (ln < 60) {
        int mvl = ln / 15, row = ln - mvl * 15;
        int mv = w * 4 + mvl;
        rIdx[mv][row] = words[(base + mv) * LW + row] * LW + row;
    }
    if (ln < 8) {
        int mvl = ln >> 1, f = ln & 1;
        int n = base + w * 4 + mvl;
        int v = (f == 0) ? (rowsI[n] * 30 + colsI[n] * 2 + dirsI[n])
                         : (450 + min(scoresI[n], 99));
        meta[w * 4 + mvl][f] = v;
    }
    __builtin_amdgcn_wave_barrier();

    // -------- phase 1: 8 H-gathers in flight per wave (2 moves x 4 pairs)
    const int mv0 = hw * 2, mv1 = mv0 + 1;
    float2 h0[4], h1[4];
    int ll[4], mm[4];
    #pragma unroll
    for (int k = 0; k < 4; ++k) {
        int p = j + 32 * k;
        if (p < 120) {
            int lm = PAIR_LUT[p];
            ll[k] = lm >> 4; mm[k] = lm & 15;
            h0[k] = H[(size_t)rIdx[mv0][ll[k]] * GSH + rIdx[mv0][mm[k]]];
            h1[k] = H[(size_t)rIdx[mv1][ll[k]] * GSH + rIdx[mv1][mm[k]]];
        }
    }
    #pragma unroll
    for (int k = 0; k < 4; ++k) {
        int p = j + 32 * k;
        if (p < 120) {
            S[mv0][ll[k]][mm[k]] = h0[k].x;
            S[mv0][mm[k]][ll[k]] = h0[k].y;
            S[mv1][ll[k]][mm[k]] = h1[k].x;
            S[mv1][mm[k]][ll[k]] = h1[k].y;
        }
    }
    __builtin_amdgcn_wave_barrier();

    // -------- row softmax: lane ln<60 -> (move w*4 + ln/15, row ln%15)
    if (ln < 60) {
        int mvl = ln / 15, row = ln - mvl * 15;
        int mv = w * 4 + mvl;
        float s[LW];
        #pragma unroll
        for (int m = 0; m < LW; ++m) s[m] = S[mv][row][m];
        float mx = s[0];
        #pragma unroll
        for (int m = 1; m < LW; ++m) mx = fmaxf(mx, s[m]);
        float sum = 0.f;
        #pragma unroll
        for (int m = 0; m < LW; ++m) { s[m] = __expf(s[m] - mx); sum += s[m]; }
        float inv = 1.0f / sum;
        #pragma unroll
        for (int m = 0; m < LW; ++m) S[mv][row][m] = s[m] * inv;
    }
    __builtin_amdgcn_wave_barrier();

    // -------- column sums: lane ln<60 -> (move, column)
    if (ln < 60) {
        int mvl = ln / 15, col = ln - mvl * 15;
        int mv = w * 4 + mvl;
        float acc = 0.f;
        #pragma unroll
        for (int l = 0; l < LW; ++l) acc += S[mv][l][col];
        csum[mv][col] = acc;
    }
    __builtin_amdgcn_wave_barrier();

    // -------- phase 2: wave w handles moves 4w..4w+3, two at a time
    const int d0 = ln * 4;
    const unsigned short* VT16 = (const unsigned short*)VT;
    const unsigned short* EP16 = (const unsigned short*)EP2;
    #pragma unroll 2
    for (int s2 = 0; s2 < 4; ++s2) {
        const int i = w * 4 + s2;
        const int n = base + i;
        // batch 1: 2 bf16 epilogue rows + first 8 VT rows
        ushort4 ve = *(const ushort4*)(EP16 + meta[i][0] * DIM + d0);
        ushort4 se = *(const ushort4*)(EP16 + meta[i][1] * DIM + d0);
        ushort4 va[8];
        #pragma unroll
        for (int m = 0; m < 8; ++m)
            va[m] = *(const ushort4*)(VT16 + (size_t)rIdx[i][m] * DIM + d0);
        float wx = 0.f, wy = 0.f, wz = 0.f, ww = 0.f;
        #pragma unroll
        for (int m = 0; m < 8; ++m) {
            float c = csum[i][m];
            wx += c * b2f(va[m].x); wy += c * b2f(va[m].y);
            wz += c * b2f(va[m].z); ww += c * b2f(va[m].w);
        }
        // batch 2: remaining 7 VT rows
        ushort4 vb[7];
        #pragma unroll
        for (int m = 0; m < 7; ++m)
            vb[m] = *(const ushort4*)(VT16 + (size_t)rIdx[i][8 + m] * DIM + d0);
        #pragma unroll
        for (int m = 0; m < 7; ++m) {
            float c = csum[i][8 + m];
            wx += c * b2f(vb[m].x); wy += c * b2f(vb[m].y);
            wz += c * b2f(vb[m].z); ww += c * b2f(vb[m].w);
        }
        float4 res;
        res.x = 2.f * wx + b2f(ve.x) + b2f(se.x);
        res.y = 2.f * wy + b2f(ve.y) + b2f(se.y);
        res.z = 2.f * wz + b2f(ve.z) + b2f(se.z);
        res.w = 2.f * ww + b2f(ve.w) + b2f(se.w);
        *(float4*)&out[(size_t)n * DIM + d0] = res;
    }
}

extern "C" void kernel_launch(void* const* d_in, const int* in_sizes, int n_in,
                              void* d_out, int out_size, void* d_ws, size_t ws_size,
                              hipStream_t stream)
{
    const int*   words      = (const int*)d_in[0];
    const int*   rowsI      = (const int*)d_in[1];
    const int*   colsI      = (const int*)d_in[2];
    const int*   dirsI      = (const int*)d_in[3];
    const int*   scoresI    = (const int*)d_in[4];
    const float* letter_emb = (const float*)d_in[5];
    const float* positional = (const float*)d_in[6];
    const float* Wq         = (const float*)d_in[7];
    const float* bq         = (const float*)d_in[8];
    const float* Wk         = (const float*)d_in[9];
    const float* bk         = (const float*)d_in[10];
    const float* Wv         = (const float*)d_in[11];
    const float* bv         = (const float*)d_in[12];
    const float* row_emb    = (const float*)d_in[13];
    const float* col_emb    = (const float*)d_in[14];
    const float* dir_emb    = (const float*)d_in[15];
    const float* score_emb  = (const float*)d_in[16];
    float* out = (float*)d_out;

    // workspace: QT f32 | KT f32 | H f2[405*408] | VT bf16[405*256] | EP2 bf16[550*256]
    float*  QT = (float*)d_ws;
    float*  KT = QT + NR * DIM;
    float2* Hm = (float2*)(KT + NR * DIM);
    __hip_bfloat16* VT  = (__hip_bfloat16*)((char*)Hm + (size_t)NR * GSH * sizeof(float2));
    __hip_bfloat16* EP2 = VT + (size_t)NR * DIM;

    qkv_gemm<<<450, 256, 0, stream>>>(letter_emb, positional, Wq, bq, Wk, bk,
                                      Wv, bv, row_emb, col_emb, dir_emb,
                                      score_emb, QT, KT, VT, EP2);
    h_matrix<<<676, 256, 0, stream>>>(QT, KT, Hm);
    moves_kernel<<<NMOV / MPB, 256, 0, stream>>>(words, rowsI, colsI, dirsI,
                                                 scoresI, Hm, VT, EP2, out);
}